// Round 4
// baseline (33333.975 us; speedup 1.0000x reference)
//
#include <hip/hip_runtime.h>
#include <hip/hip_bf16.h>

#define N_NODES 16384
#define E_EDGESN (16384*32)
#define FEAT 512
#define EMB 256
#define HID 512
#define G4 2048      // 4*HID
#define XDIM 512     // 2*EMB
#define NWG 16       // worker workgroups (all on ONE XCD)
#define NLAUNCH 128  // launched wgs; pigeonhole: >= 8*15+1 guarantees some XCD gets 16
#define UPW 32       // hidden units per worker wg

typedef __attribute__((ext_vector_type(8))) short bf16x8;
typedef __attribute__((ext_vector_type(4))) float f32x4;

__device__ __forceinline__ float b2f(unsigned short u) {
  union { unsigned int i; float f; } v; v.i = ((unsigned int)u) << 16; return v.f;
}
__device__ __forceinline__ unsigned short f2b(float f) {
  union { float f; unsigned int i; } v; v.f = f;
  unsigned int x = v.i;
  unsigned int r = (x + 0x7FFFu + ((x >> 16) & 1u)) >> 16;
  return (unsigned short)r;
}
__device__ __forceinline__ float fast_sigmoid(float x) {
  return __builtin_amdgcn_rcpf(1.0f + __expf(-x));
}
__device__ __forceinline__ float fast_tanh(float x) {
  // 1 - 2/(exp(2x)+1); saturates correctly for |x| large
  return fmaf(-2.0f, __builtin_amdgcn_rcpf(1.0f + __expf(2.0f * x)), 1.0f);
}

// ---------------- K0: dtype detection (bf16 vs fp32 inputs) ----------------
__global__ __launch_bounds__(256) void k_detect(const unsigned* __restrict__ w,
                                                unsigned* __restrict__ flag) {
  __shared__ int cnt;
  if (threadIdx.x == 0) cnt = 0;
  __syncthreads();
  int hits = 0;
#pragma unroll
  for (int j = 0; j < 4; ++j) {
    unsigned wv = w[threadIdx.x * 4 + j];
    unsigned e = (wv >> 7) & 0xFFu;
    if ((e >= 90u && e <= 126u) || ((wv & 0xFFFFu) == 0u)) hits++;
  }
  atomicAdd(&cnt, hits);
  __syncthreads();
  if (threadIdx.x == 0) *flag = (cnt < 512) ? 1u : 0u;   // 1 = fp32 inputs
}

// ---------------- K1: canonicalize float tensor to bf16 ----------------
__global__ void k_convert(const void* __restrict__ src, unsigned short* __restrict__ dst,
                          int n, const unsigned* __restrict__ flag) {
  int i = blockIdx.x * blockDim.x + threadIdx.x;
  if (i >= n) return;
  if (*flag) dst[i] = f2b(((const float*)src)[i]);
  else       dst[i] = ((const unsigned short*)src)[i];
}

// ---------------- K2: tag histogram scatter ----------------
__global__ void k_hist(const int* __restrict__ nid, const int* __restrict__ ntag,
                       unsigned* __restrict__ hist) {
  int e = blockIdx.x * blockDim.x + threadIdx.x;
  if (e < E_EDGESN)
    atomicAdd(&hist[(size_t)nid[e] * FEAT + ntag[e]], 1u);
}

// ---------------- K3: build x = [node_emb | nb_emb] as bf16 ----------------
__global__ __launch_bounds__(256) void k_build_x(
    const int* __restrict__ tags, const unsigned* __restrict__ hist,
    const unsigned short* __restrict__ Wemb, const unsigned short* __restrict__ bemb,
    unsigned short* __restrict__ x) {
  __shared__ int f_lds[160];
  __shared__ float c_lds[160];
  __shared__ int nlist;
  int n = blockIdx.x, c = threadIdx.x;
  if (c == 0) nlist = 0;
  __syncthreads();
  for (int f = c; f < FEAT; f += 256) {
    unsigned cnt = hist[(size_t)n * FEAT + f];
    if (cnt) {
      int idx = atomicAdd(&nlist, 1);
      if (idx < 160) { f_lds[idx] = f; c_lds[idx] = (float)cnt; }
    }
  }
  __syncthreads();
  int m = nlist; if (m > 160) m = 160;
  float be = b2f(bemb[c]);
  int tg = tags[n];
  x[(size_t)n * XDIM + c] = f2b(b2f(Wemb[(size_t)tg * EMB + c]) + be);
  float acc = be;
  for (int j = 0; j < m; ++j)
    acc += c_lds[j] * b2f(Wemb[(size_t)f_lds[j] * EMB + c]);
  x[(size_t)n * XDIM + EMB + c] = f2b(acc);
}

// ---------------- K4: pre = x @ W_ih^T + b_lstm (MFMA bf16) ----------------
// Output PERMUTED: prep[t][unit*4 + gate] so the scan loads one unit's 4 gate
// pre-activations with a single 8B load. gate = nn>>9, unit = nn&511.
__global__ __launch_bounds__(256) void k_gemm_pre(
    const unsigned short* __restrict__ x, const unsigned short* __restrict__ Wih,
    const unsigned short* __restrict__ blstm, unsigned short* __restrict__ pre) {
  int wave = threadIdx.x >> 6, lane = threadIdx.x & 63;
  int row = lane & 15, quad = lane >> 4;
  int mband = blockIdx.y * 64 + wave * 16;
  int nbase = blockIdx.x * 128;
  f32x4 acc[8] = {};
  const unsigned short* ap = x + (size_t)(mband + row) * XDIM + quad * 8;
  const unsigned short* bp0 = Wih + (size_t)(nbase + row) * XDIM + quad * 8;
  for (int kc = 0; kc < 16; ++kc) {
    bf16x8 af = *(const bf16x8*)(ap + kc * 32);
#pragma unroll
    for (int nt = 0; nt < 8; ++nt) {
      bf16x8 bf = *(const bf16x8*)(bp0 + (size_t)nt * 16 * XDIM + kc * 32);
      acc[nt] = __builtin_amdgcn_mfma_f32_16x16x32_bf16(af, bf, acc[nt], 0, 0, 0);
    }
  }
#pragma unroll
  for (int nt = 0; nt < 8; ++nt) {
    int nn = nbase + nt * 16 + row;
    float bv = b2f(blstm[nn]);
    int pn = ((nn & 511) << 2) | (nn >> 9);   // unit*4 + gate
#pragma unroll
    for (int i = 0; i < 4; ++i) {
      int mm = mband + quad * 4 + i;
      pre[(size_t)mm * G4 + pn] = f2b(acc[nt][i] + bv);
    }
  }
}

// ---------------- K5: XCD-local persistent LSTM scan ----------------
// NLAUNCH wgs race to register; first XCD to collect NWG wgs wins; its NWG wgs
// (ranks 0..15) are the workers, everyone else exits. Workers exchange h via
// tag-in-data words in global memory: stores sc0+sc1 (write through shared
// XCD-L2 + LLC), polls sc0 (hit shared L2, ~200-300 cyc). Fallback latch to
// agent-scope polling guarantees progress if the L2 path assumption fails.
// Mapping: 16-lane group owns ONE unit's 4 gate rows; k = 32j + 2s + {0,1}.
// The poll is itself the producer barrier (no consumer can pass until every
// unit group in every wg stored), so only one __syncthreads per step.
__global__ __launch_bounds__(512, 2) void k_scan(
    const unsigned short* __restrict__ Whh, const unsigned short* __restrict__ prep,
    unsigned* __restrict__ hw, float* __restrict__ embed, int* __restrict__ elect) {
  __shared__ float h_lds[HID];
  __shared__ int rank_s;
  int tid = threadIdx.x;

  if (tid == 0) {
    unsigned xcd;
    asm volatile("s_getreg_b32 %0, hwreg(HW_REG_XCC_ID)" : "=s"(xcd));
    xcd &= 7u;
    int idx = atomicAdd(&elect[xcd], 1);
    int rank = -1;
    if (idx < NWG) {
      if (idx == NWG - 1) atomicCAS(&elect[8], -1, (int)xcd);
      int w;
      while ((w = __hip_atomic_load(&elect[8], __ATOMIC_RELAXED,
                                    __HIP_MEMORY_SCOPE_AGENT)) == -1)
        __builtin_amdgcn_s_sleep(8);
      if (w == (int)xcd) rank = idx;
    }
    rank_s = rank;
  }
  __syncthreads();
  int wg = rank_s;
  if (wg < 0) return;

  int ug = tid >> 4;           // unit within wg [0,32)
  int s  = tid & 15;           // k-slice
  int unit = wg * UPW + ug;    // global unit [0,512)

  // W_hh rows for this unit's 4 gates, k interleaved: k = 32j + 2s + {0,1}
  float wreg[4][32];
#pragma unroll
  for (int g = 0; g < 4; ++g) {
    const unsigned short* wp = Whh + (size_t)(g * HID + unit) * HID;
#pragma unroll
    for (int j = 0; j < 16; ++j) {
      wreg[g][2 * j]     = b2f(wp[32 * j + 2 * s]);
      wreg[g][2 * j + 1] = b2f(wp[32 * j + 2 * s + 1]);
    }
  }

  ushort4 pc = *(const ushort4*)(prep + (size_t)unit * 4);   // t=0 gates i,f,g,o
  float cstate = 0.0f, eacc = 0.0f;
  h_lds[tid] = 0.0f;
  __syncthreads();

  unsigned long long hwB = (unsigned long long)hw;
  int pollslow = 0;

  for (int t = 0; t < N_NODES; ++t) {
    // ---- matvec over h(t-1) in LDS: conflict-free float2, 4-way bcast ----
    float a0 = 0.f, a1 = 0.f, a2 = 0.f, a3 = 0.f;
    const float2* hb = (const float2*)h_lds;
#pragma unroll
    for (int j = 0; j < 16; ++j) {
      float2 hv = hb[j * 16 + s];
      a0 += wreg[0][2*j] * hv.x + wreg[0][2*j+1] * hv.y;
      a1 += wreg[1][2*j] * hv.x + wreg[1][2*j+1] * hv.y;
      a2 += wreg[2][2*j] * hv.x + wreg[2][2*j+1] * hv.y;
      a3 += wreg[3][2*j] * hv.x + wreg[3][2*j+1] * hv.y;
    }
#pragma unroll
    for (int off = 1; off < 16; off <<= 1) {
      a0 += __shfl_xor(a0, off);
      a1 += __shfl_xor(a1, off);
      a2 += __shfl_xor(a2, off);
      a3 += __shfl_xor(a3, off);
    }

    unsigned tagw = (unsigned)t;
    unsigned long long sbase = hwB + (unsigned)((t & 1) << 12);

    if (s == 0) {
      float gi = fast_sigmoid(a0 + b2f(pc.x));
      float gf = fast_sigmoid(a1 + b2f(pc.y));
      float gg = fast_tanh   (a2 + b2f(pc.z));
      float go = fast_sigmoid(a3 + b2f(pc.w));
      cstate = gf * cstate + gi * gg;
      float hn = go * fast_tanh(cstate);
      eacc += hn;
      if (t < N_NODES - 1) {
        union { float f; unsigned u; } cu; cu.f = hn;
        unsigned long long sv =
            ((unsigned long long)((cu.u << 16) | tagw) << 32) |
            (unsigned long long)((cu.u & 0xFFFF0000u) | tagw);
        unsigned long long sa = sbase + 8u * (unsigned)unit;
        asm volatile("global_store_dwordx2 %0, %1, off sc0 sc1"
                     :: "v"(sa), "v"(sv) : "memory");
      }
    }
    // prefetch next step's pre gates (latency hidden behind the poll)
    if (s == 0 && (t + 1) < N_NODES)
      pc = *(const ushort4*)(prep + (size_t)(t + 1) * G4 + unit * 4);

    if (t < N_NODES - 1) {
      unsigned long long pa = sbase + 8u * (unsigned)tid;
      unsigned long long v64;
      unsigned v0, v1;
      int spins = 0;
      for (;;) {
        if (!pollslow) {
          asm volatile("global_load_dwordx2 %0, %1, off sc0\n\ts_waitcnt vmcnt(0)"
                       : "=v"(v64) : "v"(pa) : "memory");
          v0 = (unsigned)v64; v1 = (unsigned)(v64 >> 32);
          if ((((v0 ^ tagw) | (v1 ^ tagw)) & 0xFFFFu) == 0u) break;
          if (++spins > 4096) pollslow = 1;   // latch: L2 fast path broken
        } else {
          unsigned* pp = (unsigned*)(uintptr_t)pa;
          v0 = __hip_atomic_load(pp,     __ATOMIC_RELAXED, __HIP_MEMORY_SCOPE_AGENT);
          v1 = __hip_atomic_load(pp + 1, __ATOMIC_RELAXED, __HIP_MEMORY_SCOPE_AGENT);
          if ((((v0 ^ tagw) | (v1 ^ tagw)) & 0xFFFFu) == 0u) break;
          __builtin_amdgcn_s_sleep(1);
        }
      }
      union { unsigned u; float f; } rc; rc.u = (v0 & 0xFFFF0000u) | (v1 >> 16);
      h_lds[tid] = rc.f;
      __syncthreads();
    }
  }
  if (s == 0) embed[unit] = eacc;
}

// ---------------- K6: MLP head + log_softmax ----------------
__global__ __launch_bounds__(512) void k_head(
    const float* __restrict__ embed, const unsigned short* __restrict__ W1,
    const unsigned short* __restrict__ b1, const unsigned short* __restrict__ W2,
    const unsigned short* __restrict__ b2, void* __restrict__ out,
    const unsigned* __restrict__ flag) {
  __shared__ float e_s[HID], h1_s[HID];
  __shared__ float lg[16];
  int tid = threadIdx.x;
  e_s[tid] = embed[tid];
  __syncthreads();
  float sum = b2f(b1[tid]);
  for (int i = 0; i < HID; ++i)
    sum += e_s[i] * b2f(W1[(size_t)i * HID + tid]);
  h1_s[tid] = fmaxf(sum, 0.0f);
  __syncthreads();
  if (tid < 10) {
    float l = b2f(b2[tid]);
    for (int j = 0; j < HID; ++j)
      l += h1_s[j] * b2f(W2[(size_t)j * 10 + tid]);
    lg[tid] = l;
  }
  __syncthreads();
  if (tid == 0) {
    float m = -1e30f;
    for (int c = 0; c < 10; ++c) m = fmaxf(m, lg[c]);
    float se = 0.f;
    for (int c = 0; c < 10; ++c) se += expf(lg[c] - m);
    float lse = m + logf(se);
    if (*flag) {
      for (int c = 0; c < 10; ++c) ((float*)out)[c] = lg[c] - lse;
    } else {
      for (int c = 0; c < 10; ++c) ((unsigned short*)out)[c] = f2b(lg[c] - lse);
    }
  }
}

extern "C" void kernel_launch(void* const* d_in, const int* in_sizes, int n_in,
                              void* d_out, int out_size, void* d_ws, size_t ws_size,
                              hipStream_t stream) {
  const int* node_tags = (const int*)d_in[0];
  const int* nid = (const int*)d_in[1];
  const int* ntag = (const int*)d_in[2];
  // d_in[3] = label, unused

  char* ws = (char*)d_ws;
  unsigned short* pre  = (unsigned short*)ws;                     // 67,108,864
  unsigned short* x    = (unsigned short*)(ws + 67108864);        // 16,777,216
  unsigned*       hist = (unsigned*)(ws + 83886080);              // 33,554,432
  char* tail = ws + 117440512;
  unsigned* hw    = (unsigned*)tail;                              // 8192 B (NOT zeroed: poison tag 0xAAAA never matches t<=0x3FFF)
  unsigned* flag  = (unsigned*)(tail + 8192);
  float*    embed = (float*)(tail + 8448);                        // 2048 B
  int*      elect = (int*)(tail + 10496);                         // 64 B: [0..7] per-XCD cnt, [8] winner
  char* wc = ws + 117456896;                                      // bf16 weight copies
  unsigned short* Wemb_c  = (unsigned short*)(wc);
  unsigned short* bemb_c  = (unsigned short*)(wc + 262144);
  unsigned short* Wih_c   = (unsigned short*)(wc + 262656);
  unsigned short* Whh_c   = (unsigned short*)(wc + 2359808);
  unsigned short* blstm_c = (unsigned short*)(wc + 4456960);
  unsigned short* W1_c    = (unsigned short*)(wc + 4461056);
  unsigned short* b1_c    = (unsigned short*)(wc + 4985344);
  unsigned short* W2_c    = (unsigned short*)(wc + 4986368);
  unsigned short* b2_c    = (unsigned short*)(wc + 4996608);

  hipMemsetAsync(hist, 0, 33554432, stream);       // hist must start at zero
  hipMemsetAsync(elect, 0, 32, stream);            // per-XCD counters = 0
  hipMemsetAsync(elect + 8, 0xFF, 4, stream);      // winner = -1

  k_detect<<<1, 256, 0, stream>>>((const unsigned*)d_in[6], flag);

  struct { const void* s; unsigned short* d; int n; } cv[9] = {
    { d_in[4],  Wemb_c,  FEAT * EMB },
    { d_in[5],  bemb_c,  EMB },
    { d_in[6],  Wih_c,   G4 * XDIM },
    { d_in[7],  Whh_c,   G4 * HID },
    { d_in[8],  blstm_c, G4 },
    { d_in[9],  W1_c,    HID * HID },
    { d_in[10], b1_c,    HID },
    { d_in[11], W2_c,    HID * 10 },
    { d_in[12], b2_c,    10 },
  };
  for (int i = 0; i < 9; ++i)
    k_convert<<<(cv[i].n + 255) / 256, 256, 0, stream>>>(cv[i].s, cv[i].d, cv[i].n, flag);

  k_hist<<<E_EDGESN / 256, 256, 0, stream>>>(nid, ntag, hist);
  k_build_x<<<N_NODES, 256, 0, stream>>>(node_tags, hist, Wemb_c, bemb_c, x);
  k_gemm_pre<<<dim3(G4 / 128, N_NODES / 64), 256, 0, stream>>>(x, Wih_c, blstm_c, pre);
  k_scan<<<NLAUNCH, 512, 0, stream>>>(Whh_c, pre, hw, embed, elect);
  k_head<<<1, 512, 0, stream>>>(embed, W1_c, b1_c, W2_c, b2_c, d_out, flag);
}